// Round 10
// baseline (2672.719 us; speedup 1.0000x reference)
//
#include <hip/hip_runtime.h>

#define B 8
#define N 8192
#define S 2048
#define K 32
#define TPB 512           // all blocks: 8 waves
#define PPT (N / TPB)     // 16 contiguous points per FPS thread
#define NPAIR (PPT / 2)   // 8 packed pairs
#define CHUNK_STEP 128    // FPS publish cadence
#define WPB 31            // worker blocks per batch
#define WVB (WPB * 8)     // 248 KNN waves per batch (stride)

typedef float v2f __attribute__((ext_vector_type(2)));

// Exact (no-FMA, left-to-right) squared distance to match numpy fp32:
// ((dx*dx + dy*dy) + dz*dz). FPS argmax is a chaotic recurrence; any ulp
// difference diverges the center sequence. Verified absmax==0 (R1-R9).
__device__ __forceinline__ float sqdist3(float ax, float ay, float az,
                                         float bx, float by, float bz) {
    float dx = ax - bx, dy = ay - by, dz = az - bz;
    return __fadd_rn(__fadd_rn(__fmul_rn(dx, dx), __fmul_rn(dy, dy)),
                     __fmul_rn(dz, dz));
}

template <int CTRL>
__device__ __forceinline__ float dpp_fmax(float v) {
    const int iv = __float_as_int(v);
    const int sh = __builtin_amdgcn_update_dpp(iv, iv, CTRL, 0xF, 0xF, false);
    return fmaxf(v, __int_as_float(sh));
}
__device__ __forceinline__ float wave_fmax_dpp(float v) {
    v = dpp_fmax<0x111>(v);  // row_shr:1
    v = dpp_fmax<0x112>(v);  // row_shr:2
    v = dpp_fmax<0x114>(v);  // row_shr:4
    v = dpp_fmax<0x118>(v);  // row_shr:8
    v = dpp_fmax<0x142>(v);  // row_bcast:15
    v = dpp_fmax<0x143>(v);  // row_bcast:31 -> lane 63 = wave max
    return __int_as_float(__builtin_amdgcn_readlane(__float_as_int(v), 63));
}

// ---------------------------------------------------------------------------
// Fused producer-consumer (R9-verified structure), 256 blocks x 512 threads.
//  - blocks 0..7: FPS producer. R10 change: packed v2f hot loop (v_pk_*_f32
//    halves update-phase issue; per-half rounding == scalar, R7-verified
//    bit-exact). One barrier/step; publish float4/wave; serial 8-slot scan.
//    Every 128 steps: barrier, copy chunk LDS->global, barrier, t0
//    agent-RELEASE progress[b] (L2 writeback -> cross-XCD safe).
//  - blocks 8..255: strided KNN workers, wave w handles centers w, w+248,...
//    waiting per-center on progress[b] > s (acquire + s_sleep backoff).
// Tie-break invariants: FPS (max dist, min gid) — pairs scanned ascending,
// halves in order => first index; KNN (d, idx) lexicographic == stable top_k.
// ---------------------------------------------------------------------------
__global__ __launch_bounds__(TPB, 2) void fused_kernel(
    const float* __restrict__ xyz, float* __restrict__ out,
    float* __restrict__ centers, unsigned* __restrict__ progress) {
#pragma clang fp contract(off)
    const int blk = blockIdx.x;
    const int t = threadIdx.x;
    const int lane = t & 63;

    if (blk < B) {
        // =================== FPS producer ===================
        const int b = blk;
        const float* xb = xyz + (size_t)b * N * 3;
        float* cb = centers + (size_t)b * S * 3;
        const int wid = t >> 6;

        // load 16 contiguous points (48 floats = 12 float4), deinterleave
        // into packed pairs X[j]=(x_{2j},x_{2j+1}) etc.
        v2f X[NPAIR], Y[NPAIR], Z[NPAIR], MD[NPAIR];
        {
            float raw[3 * PPT];
            const float4* src = (const float4*)(xb + 3 * PPT * t);
#pragma unroll
            for (int i = 0; i < 3 * PPT / 4; ++i) {
                const float4 v = src[i];
                raw[4 * i + 0] = v.x; raw[4 * i + 1] = v.y;
                raw[4 * i + 2] = v.z; raw[4 * i + 3] = v.w;
            }
#pragma unroll
            for (int j = 0; j < NPAIR; ++j) {
                X[j] = (v2f){raw[6 * j + 0], raw[6 * j + 3]};
                Y[j] = (v2f){raw[6 * j + 1], raw[6 * j + 4]};
                Z[j] = (v2f){raw[6 * j + 2], raw[6 * j + 5]};
                MD[j] = (v2f){INFINITY, INFINITY};
            }
        }

        __shared__ float4 pub[2][8];       // per-wave {wmax,x,y,z}, dbuf
        __shared__ float cent[S * 3];      // centers staged in LDS (24 KB)

        float px = xb[0], py = xb[1], pz = xb[2];   // step 0: point 0
        if (t == 0) { cent[0] = px; cent[1] = py; cent[2] = pz; }

        for (int s = 1; s < S; ++s) {
            // --- packed update: d = (dx*dx + dy*dy) + dz*dz per half
            const v2f P_ = (v2f){px, px}, Q_ = (v2f){py, py}, R_ = (v2f){pz, pz};
            v2f pmax[NPAIR];
#pragma unroll
            for (int j = 0; j < NPAIR; ++j) {
                const v2f dx = X[j] - P_, dy = Y[j] - Q_, dz = Z[j] - R_;
                const v2f d = (dx * dx + dy * dy) + dz * dz;
                const v2f m = {fminf(MD[j].x, d.x), fminf(MD[j].y, d.y)};
                MD[j] = m;
                pmax[j] = m;
            }
            // packed max tree (7 pk_max) + one scalar combine
#pragma unroll
            for (int st = 1; st < NPAIR; st <<= 1)
#pragma unroll
                for (int j = 0; j < NPAIR; j += 2 * st) {
                    pmax[j] = (v2f){fmaxf(pmax[j].x, pmax[j + st].x),
                                    fmaxf(pmax[j].y, pmax[j + st].y)};
                }
            const float best = fmaxf(pmax[0].x, pmax[0].y);

            // --- wave max (DPP) + first-lane tie-break via ballot
            const float wmax = wave_fmax_dpp(best);
            const unsigned long long mb = __ballot(best == wmax);
            const int ol = (int)__builtin_ctzll(mb);

            // --- owner: first-match re-derive over pairs asc, halves in
            //     order (== lowest local i == lowest gid), publish float4
            const int pb = s & 1;
            if (lane == ol) {
                float wx = X[0].x, wy = Y[0].x, wz = Z[0].x;
                bool found = (MD[0].x == wmax);
#pragma unroll
                for (int j = 0; j < NPAIR; ++j) {
#pragma unroll
                    for (int h = 0; h < 2; ++h) {
                        if (j == 0 && h == 0) continue;
                        const float mv = h ? MD[j].y : MD[j].x;
                        const bool hit = !found && (mv == wmax);
                        wx = hit ? (h ? X[j].y : X[j].x) : wx;
                        wy = hit ? (h ? Y[j].y : Y[j].x) : wy;
                        wz = hit ? (h ? Z[j].y : Z[j].x) : wz;
                        found = found || hit;
                    }
                }
                pub[pb][wid] = make_float4(wmax, wx, wy, wz);
            }
            __syncthreads();               // the ONLY per-step barrier

            // --- serial scan of 8 wave winners (strict > -> lowest wid ties)
            float4 v0 = pub[pb][0];
            float gmax = v0.x;
            px = v0.y; py = v0.z; pz = v0.w;
#pragma unroll
            for (int w = 1; w < 8; ++w) {
                const float4 u = pub[pb][w];
                const bool g = u.x > gmax;
                gmax = g ? u.x : gmax;
                px = g ? u.y : px;
                py = g ? u.z : py;
                pz = g ? u.w : pz;
            }
            if (t == 0) {
                cent[3 * s + 0] = px;
                cent[3 * s + 1] = py;
                cent[3 * s + 2] = pz;
            }

            // ---- chunk publish: barrier, copy, barrier (vmcnt drain), release
            if ((s & (CHUNK_STEP - 1)) == (CHUNK_STEP - 1)) {
                __syncthreads();           // t0's cent[3s] visible to copiers
                const int base = 3 * (s - (CHUNK_STEP - 1));
                if (t < 3 * CHUNK_STEP) cb[base + t] = cent[base + t];
                __syncthreads();           // drains copiers' stores (vmcnt0)
                if (t == 0)
                    __hip_atomic_store(&progress[b], (unsigned)(s + 1),
                                       __ATOMIC_RELEASE, __HIP_MEMORY_SCOPE_AGENT);
            }
        }
    } else {
        // ======================= KNN workers ===============================
        const int w = blk - B;
        const int b = w & 7;               // same XCD as FPS block b (%8 rr)
        const int wchunk = w >> 3;         // 0..30
        const int waveid = wchunk * 8 + (t >> 6);   // 0..247 within batch
        const float* xb = xyz + (size_t)b * N * 3;

        unsigned seen = 0;                 // register-cached progress[b]
        for (int s = waveid; s < S; s += WVB) {
            while (seen <= (unsigned)s) {
                seen = __hip_atomic_load(&progress[b], __ATOMIC_ACQUIRE,
                                         __HIP_MEMORY_SCOPE_AGENT);
                if (seen <= (unsigned)s) __builtin_amdgcn_s_sleep(64);
            }

            const float* c = centers + (size_t)(b * S + s) * 3;
            const float cx = c[0], cy = c[1], cz = c[2];

            unsigned long long P = ~0ULL;   // lanes 0..31: sorted top-32 (asc)
            unsigned long long tau = ~0ULL;

            for (int i = 0; i < N / 64; ++i) {
                const int p = (i << 6) + lane;
                const float* q = xb + 3 * p;
                const float d = sqdist3(q[0], q[1], q[2], cx, cy, cz);
                const unsigned long long cand =
                    ((unsigned long long)__float_as_uint(d) << 32) | (unsigned)p;
                bool alive = cand < tau;
                unsigned long long mask = __ballot(alive);
                while (mask) {
                    const int src = __builtin_ctzll(mask);
                    const unsigned long long bc = __shfl(cand, src);
                    unsigned long long up = __shfl_up(P, 1);
                    if (lane == 0) up = bc;
                    const bool gt = P > bc;
                    const unsigned long long shifted = (up > bc) ? up : bc;
                    P = gt ? shifted : P;
                    tau = __shfl(P, 31);
                    if (lane == src) alive = false;
                    alive = alive && (cand < tau);
                    mask = __ballot(alive);
                }
            }

            if (lane < K) {
                const unsigned nidx = (unsigned)P;
                const float* q = xb + 3 * nidx;
                float* o = out + ((size_t)(b * S + s) * K + lane) * 3;
                o[0] = q[0] - cx;
                o[1] = q[1] - cy;
                o[2] = q[2] - cz;
            }
        }
    }
}

extern "C" void kernel_launch(void* const* d_in, const int* in_sizes, int n_in,
                              void* d_out, int out_size, void* d_ws, size_t ws_size,
                              hipStream_t stream) {
    const float* xyz = (const float*)d_in[0];
    float* out = (float*)d_out;                         // neighborhood [B,S,K,3]
    float* centers = out + (size_t)B * S * K * 3;       // centers [B,S,3]
    unsigned* progress = (unsigned*)d_ws;               // [B] centers-ready count

    // d_ws is poisoned 0xAA before every timed launch -> must zero progress
    hipMemsetAsync(d_ws, 0, B * sizeof(unsigned), stream);

    fused_kernel<<<B + WPB * B, TPB, 0, stream>>>(xyz, out, centers, progress);
}